// Round 1
// baseline (11660.115 us; speedup 1.0000x reference)
//
#include <hip/hip_runtime.h>
#include <hip/hip_bf16.h>
#include <hip/hip_cooperative_groups.h>

namespace cg = cooperative_groups;

typedef __attribute__((ext_vector_type(8))) short bf16x8;
typedef __attribute__((ext_vector_type(4))) float f32x4;

#define TT 256
#define BB 64
#define HH 1024
#define G4 4096

static constexpr int NB_L0 = 32;
static constexpr int NB_L1 = 64;
static constexpr int NB = NB_L0 + NB_L1;

__device__ __forceinline__ unsigned short f2bf(float f) {
    unsigned int u = __float_as_uint(f);
    u += 0x7fffu + ((u >> 16) & 1u);   // round-to-nearest-even
    return (unsigned short)(u >> 16);
}
__device__ __forceinline__ float bf2f(unsigned short s) {
    return __uint_as_float(((unsigned int)s) << 16);
}
__device__ __forceinline__ float sigm(float x) { return 1.0f / (1.0f + __expf(-x)); }
__device__ __forceinline__ float tanh_f(float x) {
    float e = __expf(-2.0f * fabsf(x));
    float t = (1.0f - e) / (1.0f + e);
    return copysignf(t, x);
}

// ---------------- prep: bf16 conversions, bias folding, state init ----------------
__global__ void __launch_bounds__(256) prep_kernel(
    const float* __restrict__ inputs, const float* __restrict__ h0in, const float* __restrict__ c0in,
    const float* __restrict__ Wx0, const float* __restrict__ bx0,
    const float* __restrict__ Wh0, const float* __restrict__ bh0,
    const float* __restrict__ Wx1, const float* __restrict__ bx1,
    const float* __restrict__ Wh1, const float* __restrict__ bh1,
    unsigned short* __restrict__ Wx0b, unsigned short* __restrict__ Wh0b,
    unsigned short* __restrict__ Wx1b, unsigned short* __restrict__ Wh1b,
    unsigned short* __restrict__ inbf, float* __restrict__ bias0, float* __restrict__ bias1,
    unsigned short* __restrict__ h0bf, unsigned short* __restrict__ h1bf,
    float* __restrict__ c0, float* __restrict__ c1)
{
    const long long Nw  = 4194304;   // 4096*1024
    const long long Nin = 16777216;  // 64*256*1024
    const long long total = 4 * Nw + Nin + 4096 + 65536;
    for (long long idx = (long long)blockIdx.x * blockDim.x + threadIdx.x; idx < total;
         idx += (long long)gridDim.x * blockDim.x) {
        if (idx < Nw) {
            Wx0b[idx] = f2bf(Wx0[idx]);
        } else if (idx < 2 * Nw) {
            long long i = idx - Nw;      Wh0b[i] = f2bf(Wh0[i]);
        } else if (idx < 3 * Nw) {
            long long i = idx - 2 * Nw;  Wx1b[i] = f2bf(Wx1[i]);
        } else if (idx < 4 * Nw) {
            long long i = idx - 3 * Nw;  Wh1b[i] = f2bf(Wh1[i]);
        } else if (idx < 4 * Nw + Nin) {
            long long i = idx - 4 * Nw;
            int k = (int)(i & 1023);
            int t = (int)((i >> 10) & 255);
            int b = (int)(i >> 18);
            inbf[((long long)(t * 64 + b) << 10) + k] = f2bf(inputs[i]);
        } else if (idx < 4 * Nw + Nin + 4096) {
            int i = (int)(idx - (4 * Nw + Nin));
            bias0[i] = bx0[i] + bh0[i];
            bias1[i] = bx1[i] + bh1[i];
        } else {
            int i = (int)(idx - (4 * Nw + Nin + 4096));
            h0bf[65536 + i] = f2bf(h0in[i]);            // buffer 1 = state at t=-1
            h1bf[65536 + i] = f2bf(h0in[65536 + i]);
            c0[i] = c0in[i];
            c1[i] = c0in[65536 + i];
        }
    }
}

// ---------------- GEMM0: X0pre[t*64+b][n] = inputs@Wx0^T + bias0, bf16 out ----------------
__global__ void __launch_bounds__(256) gemm0_kernel(
    const unsigned short* __restrict__ A,   // [16384][1024] bf16, row = t*64+b
    const unsigned short* __restrict__ Bw,  // [4096][1024] bf16
    const float* __restrict__ bias0,
    unsigned short* __restrict__ X0pre)     // [16384][4096] bf16
{
    __shared__ __align__(16) char smem[32768];
    unsigned short* As = (unsigned short*)smem;            // [128][64] swizzled
    unsigned short* Bs = (unsigned short*)(smem + 16384);  // [128][64] swizzled
    const int tid = threadIdx.x, lane = tid & 63, wave = tid >> 6;
    const int wm = wave >> 1, wn = wave & 1;
    const int mt = blockIdx.x >> 5, nt = blockIdx.x & 31;

    f32x4 acc[4][4];
#pragma unroll
    for (int a = 0; a < 4; ++a)
#pragma unroll
        for (int b = 0; b < 4; ++b) acc[a][b] = (f32x4){0.f, 0.f, 0.f, 0.f};

    for (int kc = 0; kc < 16; ++kc) {
        __syncthreads();
#pragma unroll
        for (int p = 0; p < 4; ++p) {
            int cidx = tid + p * 256;
            int row = cidx >> 3, slot = cidx & 7;
            bf16x8 va = *reinterpret_cast<const bf16x8*>(A + (size_t)(mt * 128 + row) * 1024 + kc * 64 + slot * 8);
            *reinterpret_cast<bf16x8*>((char*)As + row * 128 + ((slot ^ (row & 7)) << 4)) = va;
            bf16x8 vb = *reinterpret_cast<const bf16x8*>(Bw + (size_t)(nt * 128 + row) * 1024 + kc * 64 + slot * 8);
            *reinterpret_cast<bf16x8*>((char*)Bs + row * 128 + ((slot ^ (row & 7)) << 4)) = vb;
        }
        __syncthreads();
#pragma unroll
        for (int kk = 0; kk < 2; ++kk) {
            int slotb = kk * 4 + (lane >> 4);
            bf16x8 af[4], bv[4];
#pragma unroll
            for (int mf = 0; mf < 4; ++mf) {
                int row = wm * 64 + mf * 16 + (lane & 15);
                af[mf] = *reinterpret_cast<const bf16x8*>((char*)As + row * 128 + ((slotb ^ (row & 7)) << 4));
            }
#pragma unroll
            for (int nf = 0; nf < 4; ++nf) {
                int row = wn * 64 + nf * 16 + (lane & 15);
                bv[nf] = *reinterpret_cast<const bf16x8*>((char*)Bs + row * 128 + ((slotb ^ (row & 7)) << 4));
            }
#pragma unroll
            for (int mf = 0; mf < 4; ++mf)
#pragma unroll
                for (int nf = 0; nf < 4; ++nf)
                    acc[mf][nf] = __builtin_amdgcn_mfma_f32_16x16x32_bf16(af[mf], bv[nf], acc[mf][nf], 0, 0, 0);
        }
    }
#pragma unroll
    for (int nf = 0; nf < 4; ++nf) {
        int n = nt * 128 + wn * 64 + nf * 16 + (lane & 15);
        float bz = bias0[n];
#pragma unroll
        for (int mf = 0; mf < 4; ++mf)
#pragma unroll
            for (int r = 0; r < 4; ++r) {
                int rg = mt * 128 + wm * 64 + mf * 16 + (lane >> 4) * 4 + r;
                X0pre[(size_t)rg * 4096 + n] = f2bf(acc[mf][nf][r] + bz);
            }
    }
}

// ---------------- persistent recurrent kernel ----------------
struct RecParams {
    const unsigned short* X0pre;
    const unsigned short* Wh0b;
    const unsigned short* Wx1b;
    const unsigned short* Wh1b;
    const float* bias1;
    unsigned short* h0bf;   // [2][64][1024]
    unsigned short* h1bf;   // [2][64][1024]
    float* c0;              // [64][1024]
    float* c1;
    float* h0f;             // latest layer0 h, fp32
    float* out;             // d_out base
};

__device__ __forceinline__ void stage_h(unsigned short* Ast, const unsigned short* src, int kc, int tid) {
    // src: [64][1024] bf16 -> Ast [64][256] bf16, XOR-swizzled 16B slots
#pragma unroll
    for (int p = 0; p < 8; ++p) {
        int cidx = tid + p * 256;
        int row = cidx >> 5;
        int slot = cidx & 31;
        bf16x8 v = *reinterpret_cast<const bf16x8*>(src + row * 1024 + kc * 256 + slot * 8);
        *reinterpret_cast<bf16x8*>((char*)Ast + row * 512 + ((slot ^ (row & 7)) << 4)) = v;
    }
}
__device__ __forceinline__ bf16x8 lds_afrag(const unsigned short* Ast, int row, int slot) {
    return *reinterpret_cast<const bf16x8*>((const char*)Ast + row * 512 + ((slot ^ (row & 7)) << 4));
}

__global__ void __launch_bounds__(256) lstm_rec(RecParams P) {
    cg::grid_group grid = cg::this_grid();
    __shared__ __align__(16) char smem[65536];
    unsigned short* Ast = (unsigned short*)smem;     // 32 KB staging
    float* combL = (float*)(smem + 32768);           // exchange buffer

    const int tid = threadIdx.x, lane = tid & 63, wave = tid >> 6;  // wave == gate index
    const int bid = blockIdx.x;

    for (int it = 0; it <= TT; ++it) {
        if (bid < NB_L0) {
            // -------- layer 0, step t = it --------
            if (it < TT) {
                const int t = it;
                const int j0 = bid * 32;
                const unsigned short* hprev = P.h0bf + (size_t)((t - 1) & 1) * (BB * HH);
                f32x4 acc[4][2];
#pragma unroll
                for (int a = 0; a < 4; ++a) {
                    acc[a][0] = (f32x4){0.f, 0.f, 0.f, 0.f};
                    acc[a][1] = (f32x4){0.f, 0.f, 0.f, 0.f};
                }
                for (int kc = 0; kc < 4; ++kc) {
                    __syncthreads();
                    stage_h(Ast, hprev, kc, tid);
                    __syncthreads();
#pragma unroll
                    for (int kk = 0; kk < 8; ++kk) {
                        int slotb = kk * 4 + (lane >> 4);
                        bf16x8 af[4];
#pragma unroll
                        for (int mf = 0; mf < 4; ++mf) af[mf] = lds_afrag(Ast, mf * 16 + (lane & 15), slotb);
                        int kglob = kc * 256 + kk * 32 + ((lane >> 4) << 3);
#pragma unroll
                        for (int nf = 0; nf < 2; ++nf) {
                            const unsigned short* wp =
                                P.Wh0b + (size_t)(wave * HH + j0 + nf * 16 + (lane & 15)) * HH + kglob;
                            bf16x8 bv = *reinterpret_cast<const bf16x8*>(wp);
#pragma unroll
                            for (int mf = 0; mf < 4; ++mf)
                                acc[mf][nf] = __builtin_amdgcn_mfma_f32_16x16x32_bf16(af[mf], bv, acc[mf][nf], 0, 0, 0);
                        }
                    }
                }
                __syncthreads();
#pragma unroll
                for (int mf = 0; mf < 4; ++mf)
#pragma unroll
                    for (int nf = 0; nf < 2; ++nf) {
                        int col = nf * 16 + (lane & 15);
#pragma unroll
                        for (int rr = 0; rr < 4; ++rr) {
                            int row = mf * 16 + (lane >> 4) * 4 + rr;
                            combL[(wave * 64 + row) * 32 + col] = acc[mf][nf][rr];
                        }
                    }
                __syncthreads();
                // gates: 64x32 elems, 8 per thread
                {
                    const int r = tid >> 2;
                    const int cb = (tid & 3) * 8;
                    const unsigned short* xp = P.X0pre + ((size_t)t * BB + r) * G4 + j0 + cb;
                    bf16x8 xi = *reinterpret_cast<const bf16x8*>(xp);
                    bf16x8 xf = *reinterpret_cast<const bf16x8*>(xp + 1024);
                    bf16x8 xg = *reinterpret_cast<const bf16x8*>(xp + 2048);
                    bf16x8 xo = *reinterpret_cast<const bf16x8*>(xp + 3072);
                    float* cp = P.c0 + r * HH + j0 + cb;
                    float* hfp = P.h0f + r * HH + j0 + cb;
                    unsigned short* hbw = P.h0bf + (size_t)(t & 1) * (BB * HH) + r * HH + j0 + cb;
                    bf16x8 hout;
#pragma unroll
                    for (int q = 0; q < 8; ++q) {
                        int c = cb + q;
                        float iv = combL[(0 * 64 + r) * 32 + c] + bf2f((unsigned short)xi[q]);
                        float fv = combL[(1 * 64 + r) * 32 + c] + bf2f((unsigned short)xf[q]);
                        float gv = combL[(2 * 64 + r) * 32 + c] + bf2f((unsigned short)xg[q]);
                        float ov = combL[(3 * 64 + r) * 32 + c] + bf2f((unsigned short)xo[q]);
                        iv = sigm(iv); fv = sigm(fv); ov = sigm(ov); gv = tanh_f(gv);
                        float cn = fv * cp[q] + iv * gv;
                        float hn = ov * tanh_f(cn);
                        cp[q] = cn;
                        hfp[q] = hn;
                        hout[q] = (short)f2bf(hn);
                    }
                    *reinterpret_cast<bf16x8*>(hbw) = hout;
                }
            }
        } else {
            // -------- layer 1, step t = it-1 --------
            if (it >= 1) {
                const int t = it - 1;
                const int lb = bid - NB_L0;
                const int j0 = lb * 16;
                f32x4 acc[4];
#pragma unroll
                for (int a = 0; a < 4; ++a) acc[a] = (f32x4){0.f, 0.f, 0.f, 0.f};
#pragma unroll 1
                for (int gm = 0; gm < 2; ++gm) {
                    const unsigned short* hsrc = (gm == 0)
                        ? P.h0bf + (size_t)(t & 1) * (BB * HH)
                        : P.h1bf + (size_t)((t - 1) & 1) * (BB * HH);
                    const unsigned short* Wb = (gm == 0) ? P.Wx1b : P.Wh1b;
                    for (int kc = 0; kc < 4; ++kc) {
                        __syncthreads();
                        stage_h(Ast, hsrc, kc, tid);
                        __syncthreads();
#pragma unroll
                        for (int kk = 0; kk < 8; ++kk) {
                            int slotb = kk * 4 + (lane >> 4);
                            bf16x8 af[4];
#pragma unroll
                            for (int mf = 0; mf < 4; ++mf) af[mf] = lds_afrag(Ast, mf * 16 + (lane & 15), slotb);
                            int kglob = kc * 256 + kk * 32 + ((lane >> 4) << 3);
                            const unsigned short* wp = Wb + (size_t)(wave * HH + j0 + (lane & 15)) * HH + kglob;
                            bf16x8 bv = *reinterpret_cast<const bf16x8*>(wp);
#pragma unroll
                            for (int mf = 0; mf < 4; ++mf)
                                acc[mf] = __builtin_amdgcn_mfma_f32_16x16x32_bf16(af[mf], bv, acc[mf], 0, 0, 0);
                        }
                    }
                }
                __syncthreads();
#pragma unroll
                for (int mf = 0; mf < 4; ++mf) {
                    int col = lane & 15;
#pragma unroll
                    for (int rr = 0; rr < 4; ++rr) {
                        int row = mf * 16 + (lane >> 4) * 4 + rr;
                        combL[(wave * 64 + row) * 16 + col] = acc[mf][rr];
                    }
                }
                __syncthreads();
                {
                    const int r = tid >> 2;
                    const int cb = (tid & 3) * 4;
                    float* cp = P.c1 + r * HH + j0 + cb;
                    unsigned short* hbw = P.h1bf + (size_t)(t & 1) * (BB * HH) + r * HH + j0 + cb;
                    float* op = P.out + ((size_t)r * TT + t) * HH + j0 + cb;
#pragma unroll
                    for (int q = 0; q < 4; ++q) {
                        int c = cb + q;
                        float iv = combL[(0 * 64 + r) * 16 + c] + P.bias1[j0 + c];
                        float fv = combL[(1 * 64 + r) * 16 + c] + P.bias1[1024 + j0 + c];
                        float gv = combL[(2 * 64 + r) * 16 + c] + P.bias1[2048 + j0 + c];
                        float ov = combL[(3 * 64 + r) * 16 + c] + P.bias1[3072 + j0 + c];
                        iv = sigm(iv); fv = sigm(fv); ov = sigm(ov); gv = tanh_f(gv);
                        float cn = fv * cp[q] + iv * gv;
                        float hn = ov * tanh_f(cn);
                        cp[q] = cn;
                        op[q] = hn;
                        hbw[q] = f2bf(hn);
                    }
                }
            }
        }
        __threadfence();
        grid.sync();
    }

    // final state copies: d_out = outputs | h_f[2] | c_f[2]
    float* hf = P.out + (size_t)BB * TT * HH;
    for (int idx = bid * 256 + tid; idx < BB * HH; idx += NB * 256) {
        int b = idx >> 10, h = idx & 1023;
        hf[idx] = P.h0f[idx];
        hf[65536 + idx] = P.out[((size_t)b * TT + (TT - 1)) * HH + h];
        hf[131072 + idx] = P.c0[idx];
        hf[196608 + idx] = P.c1[idx];
    }
}

// ---------------- host ----------------
extern "C" void kernel_launch(void* const* d_in, const int* in_sizes, int n_in,
                              void* d_out, int out_size, void* d_ws, size_t ws_size,
                              hipStream_t stream) {
    const float* inputs = (const float*)d_in[0];
    const float* h0in = (const float*)d_in[1];
    const float* c0in = (const float*)d_in[2];
    const float* Wx0 = (const float*)d_in[3];
    const float* bx0 = (const float*)d_in[4];
    const float* Wh0 = (const float*)d_in[5];
    const float* bh0 = (const float*)d_in[6];
    const float* Wx1 = (const float*)d_in[7];
    const float* bx1 = (const float*)d_in[8];
    const float* Wh1 = (const float*)d_in[9];
    const float* bh1 = (const float*)d_in[10];
    float* out = (float*)d_out;

    char* ws = (char*)d_ws;
    unsigned short* Wh0b = (unsigned short*)(ws + ((size_t)0 << 20));
    unsigned short* Wx1b = (unsigned short*)(ws + ((size_t)8 << 20));
    unsigned short* Wh1b = (unsigned short*)(ws + ((size_t)16 << 20));
    unsigned short* Wx0b = (unsigned short*)(ws + ((size_t)24 << 20));
    unsigned short* inbf = (unsigned short*)(ws + ((size_t)32 << 20));
    unsigned short* X0pre = (unsigned short*)(ws + ((size_t)64 << 20));
    float* bias0 = (float*)(ws + ((size_t)192 << 20));
    float* bias1 = (float*)(ws + ((size_t)192 << 20) + 16384);
    unsigned short* h0bf = (unsigned short*)(ws + ((size_t)192 << 20) + 32768);
    unsigned short* h1bf = h0bf + 131072;
    float* c0 = (float*)(h1bf + 131072);
    float* c1 = c0 + 65536;
    float* h0f = c1 + 65536;

    prep_kernel<<<4096, 256, 0, stream>>>(inputs, h0in, c0in, Wx0, bx0, Wh0, bh0, Wx1, bx1, Wh1, bh1,
                                          Wx0b, Wh0b, Wx1b, Wh1b, inbf, bias0, bias1,
                                          h0bf, h1bf, c0, c1);

    gemm0_kernel<<<4096, 256, 0, stream>>>(inbf, Wx0b, bias0, X0pre);

    RecParams P;
    P.X0pre = X0pre; P.Wh0b = Wh0b; P.Wx1b = Wx1b; P.Wh1b = Wh1b;
    P.bias1 = bias1; P.h0bf = h0bf; P.h1bf = h1bf;
    P.c0 = c0; P.c1 = c1; P.h0f = h0f; P.out = out;
    void* kargs[] = { &P };
    hipLaunchCooperativeKernel((const void*)lstm_rec, dim3(NB), dim3(256), kargs, 0, stream);
}